// Round 1
// baseline (849.245 us; speedup 1.0000x reference)
//
#include <hip/hip_runtime.h>
#include <hip/hip_bf16.h>

// Problem constants (match reference)
#define E_DIM 512
#define D_DIM 512
#define A_DIM 256
#define B_SZ  64
#define T_SZ  4096
#define TT    64              // t-rows per main-kernel block
#define NTB   (T_SZ / TT)     // 64 t-tiles
#define LDT   (E_DIM + 8)     // LDS row stride (bf16 elems); +8 spreads banks

typedef __bf16 bf16_t;
typedef bf16_t bf16x8 __attribute__((ext_vector_type(8)));
typedef float  f32x4  __attribute__((ext_vector_type(4)));

// round-to-nearest-even f32 -> bf16 bits
__device__ __forceinline__ unsigned short f2bf(float x) {
    union { float f; unsigned int u; } v; v.f = x;
    unsigned int u = v.u;
    return (unsigned short)((u + 0x7FFFu + ((u >> 16) & 1u)) >> 16);
}
__device__ __forceinline__ float bf_lo(unsigned int pk) {
    union { unsigned int u; float f; } v; v.u = pk << 16; return v.f;
}
__device__ __forceinline__ float bf_hi(unsigned int pk) {
    union { unsigned int u; float f; } v; v.u = pk & 0xFFFF0000u; return v.f;
}
__device__ __forceinline__ float tanh_fast(float x) {
    x = fminf(8.0f, fmaxf(-8.0f, x));            // exp(16) finite, avoids inf/inf
    float e = __expf(2.0f * x);
    return 1.0f - 2.0f * __builtin_amdgcn_rcpf(e + 1.0f);
}

// ---------------- Kernel 1: prep ----------------
// blocks 0..63   : dp[b][a] = b_enc[a] + sum_d dec[b][d]*W_dec[d][a]
// blocks 64..127 : Wt[a][e] = bf16(W_enc[e][a])   (transposed, B-frag friendly)
__global__ __launch_bounds__(256) void prep_kernel(
    const float* __restrict__ dec, const float* __restrict__ W_enc,
    const float* __restrict__ b_enc, const float* __restrict__ W_dec,
    float* __restrict__ dp, unsigned short* __restrict__ Wt)
{
    const int bid = blockIdx.x, tid = threadIdx.x;
    if (bid < B_SZ) {
        float s = b_enc[tid];
        const float* dr = dec + bid * D_DIM;
        #pragma unroll 8
        for (int d = 0; d < D_DIM; ++d)
            s = fmaf(dr[d], W_dec[d * A_DIM + tid], s);
        dp[bid * A_DIM + tid] = s;
    } else {
        int base = (bid - B_SZ) * 2048;
        #pragma unroll
        for (int i = 0; i < 8; ++i) {
            int idx = base + tid + i * 256;       // idx = a*512 + e
            int a = idx >> 9, e = idx & 511;
            Wt[idx] = f2bf(W_enc[e * A_DIM + a]);
        }
    }
}

// ---------------- Kernel 2: main (GEMM + tanh·v + exp + partial context) -----
__global__ __launch_bounds__(256, 2) void attn_main(
    const float* __restrict__ enc, const unsigned short* __restrict__ Wt,
    const float* __restrict__ dpg, const float* __restrict__ vatt,
    float* __restrict__ u_out, float* __restrict__ ctx_part)
{
    const int tb = blockIdx.x, b = blockIdx.y;
    const int tid = threadIdx.x;
    __shared__ unsigned short tile[TT * LDT];     // 66,560 B
    __shared__ float spart[4][TT];
    __shared__ float uu[TT];
    __shared__ float dp_s[A_DIM];
    __shared__ float vv[A_DIM];

    dp_s[tid] = dpg[b * A_DIM + tid];
    vv[tid]   = vatt[tid];

    // stage enc tile: 64 rows x 512 f32 -> bf16 LDS
    const float4* src = (const float4*)(enc + ((size_t)b * T_SZ + (size_t)tb * TT) * E_DIM);
    #pragma unroll 4
    for (int it = 0; it < 32; ++it) {
        int idx = tid + it * 256;                 // float4 index over 64*128
        int r = idx >> 7, c = idx & 127;
        float4 v4 = src[idx];
        ushort4 h;
        h.x = f2bf(v4.x); h.y = f2bf(v4.y); h.z = f2bf(v4.z); h.w = f2bf(v4.w);
        *(ushort4*)&tile[r * LDT + c * 4] = h;
    }
    __syncthreads();

    // GEMM: M=64(t) x N=256(a) x K=512(e); wave w owns cols [w*64, w*64+64)
    const int w = tid >> 6, lane = tid & 63;
    const int m16 = lane & 15, q = lane >> 4;
    f32x4 acc[4][4];
    #pragma unroll
    for (int mi = 0; mi < 4; ++mi)
        #pragma unroll
        for (int ni = 0; ni < 4; ++ni)
            acc[mi][ni] = (f32x4){0.f, 0.f, 0.f, 0.f};

    for (int k0 = 0; k0 < E_DIM; k0 += 32) {
        const int ka = k0 + q * 8;
        bf16x8 afr[4], bfr[4];
        #pragma unroll
        for (int mi = 0; mi < 4; ++mi)
            afr[mi] = *(const bf16x8*)&tile[(mi * 16 + m16) * LDT + ka];
        #pragma unroll
        for (int ni = 0; ni < 4; ++ni)
            bfr[ni] = *(const bf16x8*)&Wt[(w * 64 + ni * 16 + m16) * E_DIM + ka];
        #pragma unroll
        for (int mi = 0; mi < 4; ++mi)
            #pragma unroll
            for (int ni = 0; ni < 4; ++ni)
                acc[mi][ni] = __builtin_amdgcn_mfma_f32_16x16x32_bf16(
                    afr[mi], bfr[ni], acc[mi][ni], 0, 0, 0);
    }

    // epilogue: score_t = sum_a v[a]*tanh(proj + dp[a])   (b_att cancels in softmax)
    float va[4], dpv[4];
    #pragma unroll
    for (int ni = 0; ni < 4; ++ni) {
        int a = w * 64 + ni * 16 + m16;
        va[ni] = vv[a]; dpv[ni] = dp_s[a];
    }
    #pragma unroll
    for (int mi = 0; mi < 4; ++mi) {
        #pragma unroll
        for (int r = 0; r < 4; ++r) {
            float p = 0.f;
            #pragma unroll
            for (int ni = 0; ni < 4; ++ni)
                p += va[ni] * tanh_fast(acc[mi][ni][r] + dpv[ni]);
            p += __shfl_xor(p, 1); p += __shfl_xor(p, 2);
            p += __shfl_xor(p, 4); p += __shfl_xor(p, 8);
            if (m16 == 0) spart[w][mi * 16 + q * 4 + r] = p;
        }
    }
    __syncthreads();

    if (tid < TT) {
        float s = spart[0][tid] + spart[1][tid] + spart[2][tid] + spart[3][tid];
        float e = __expf(s);                      // |s| <= 16.06 -> safe
        uu[tid] = e;
        u_out[(size_t)b * T_SZ + (size_t)tb * TT + tid] = e;
    }
    __syncthreads();

    // partial context from resident LDS tile: thread owns cols 2*tid, 2*tid+1
    float c0 = 0.f, c1 = 0.f;
    #pragma unroll 4
    for (int t = 0; t < TT; ++t) {
        float ut = uu[t];
        unsigned int pk = *(const unsigned int*)&tile[t * LDT + 2 * tid];
        c0 = fmaf(ut, bf_lo(pk), c0);
        c1 = fmaf(ut, bf_hi(pk), c1);
    }
    float2 st; st.x = c0; st.y = c1;
    ((float2*)(ctx_part + ((size_t)tb * B_SZ + b) * E_DIM))[tid] = st;
}

// ---------------- Kernel 3: finalize (softmax denom, weights, context) -------
__global__ __launch_bounds__(256) void finalize_kernel(
    const float* __restrict__ u, const float* __restrict__ ctx_part,
    float* __restrict__ out)
{
    const int b = blockIdx.x, tid = threadIdx.x;
    __shared__ float red[256];
    const float* ub = u + (size_t)b * T_SZ;
    float s = 0.f;
    for (int i = tid; i < T_SZ; i += 256) s += ub[i];
    red[tid] = s; __syncthreads();
    for (int st = 128; st > 0; st >>= 1) {
        if (tid < st) red[tid] += red[tid + st];
        __syncthreads();
    }
    const float invS = 1.0f / red[0];
    // attention weights -> out[32768 ..)
    float* wout = out + B_SZ * E_DIM + (size_t)b * T_SZ;
    for (int i = tid; i < T_SZ; i += 256) wout[i] = ub[i] * invS;
    // context -> out[0 .. 32768)
    for (int e = tid; e < E_DIM; e += 256) {
        float c = 0.f;
        #pragma unroll 8
        for (int t = 0; t < NTB; ++t)
            c += ctx_part[((size_t)t * B_SZ + b) * E_DIM + e];
        out[(size_t)b * E_DIM + e] = c * invS;
    }
}

extern "C" void kernel_launch(void* const* d_in, const int* in_sizes, int n_in,
                              void* d_out, int out_size, void* d_ws, size_t ws_size,
                              hipStream_t stream) {
    const float* enc   = (const float*)d_in[0];   // (64,4096,512)
    const float* dec   = (const float*)d_in[1];   // (64,512)
    const float* W_enc = (const float*)d_in[2];   // (512,256)
    const float* b_enc = (const float*)d_in[3];   // (256,)
    const float* W_dec = (const float*)d_in[4];   // (512,256)
    const float* v_att = (const float*)d_in[5];   // (256,)
    // d_in[6] = b_att: constant shift of all scores -> cancels in softmax.
    float* out = (float*)d_out;                   // [context 64*512 | weights 64*4096]

    // ws layout (bytes): Wt bf16 [0,262144) | dp [262144,327680)
    //                    | u [327680,1376256) | ctx_part [1376256, +8MiB)
    char* ws = (char*)d_ws;
    unsigned short* Wt = (unsigned short*)(ws);
    float* dp          = (float*)(ws + 262144);
    float* u           = (float*)(ws + 327680);
    float* ctx_part    = (float*)(ws + 1376256);

    prep_kernel<<<128, 256, 0, stream>>>(dec, W_enc, b_enc, W_dec, dp, Wt);
    attn_main<<<dim3(NTB, B_SZ), 256, 0, stream>>>(enc, Wt, dp, v_att, u, ctx_part);
    finalize_kernel<<<B_SZ, 256, 0, stream>>>(u, ctx_part, out);
}

// Round 2
// 840.025 us; speedup vs baseline: 1.0110x; 1.0110x over previous
//
#include <hip/hip_runtime.h>
#include <hip/hip_bf16.h>

// Problem constants (match reference)
#define E_DIM 512
#define D_DIM 512
#define A_DIM 256
#define B_SZ  64
#define T_SZ  4096
#define TT    64              // t-rows per main-kernel block
#define NTB   (T_SZ / TT)     // 64 t-tiles
#define LDT   (E_DIM + 8)     // LDS row stride (bf16 elems); +8 -> b128 reads 2-way max

typedef __bf16 bf16_t;
typedef bf16_t bf16x8 __attribute__((ext_vector_type(8)));
typedef float  f32x4  __attribute__((ext_vector_type(4)));

// round-to-nearest-even f32 -> bf16 bits
__device__ __forceinline__ unsigned short f2bf(float x) {
    union { float f; unsigned int u; } v; v.f = x;
    unsigned int u = v.u;
    return (unsigned short)((u + 0x7FFFu + ((u >> 16) & 1u)) >> 16);
}
__device__ __forceinline__ float bf_lo(unsigned int pk) {
    union { unsigned int u; float f; } v; v.u = pk << 16; return v.f;
}
__device__ __forceinline__ float bf_hi(unsigned int pk) {
    union { unsigned int u; float f; } v; v.u = pk & 0xFFFF0000u; return v.f;
}
__device__ __forceinline__ float tanh_fast(float x) {
    x = fminf(8.0f, fmaxf(-8.0f, x));            // exp(16) finite, avoids inf/inf
    float e = __expf(2.0f * x);
    return 1.0f - 2.0f * __builtin_amdgcn_rcpf(e + 1.0f);
}

// ---------------- Kernel 1: prep ----------------
// blocks 0..63   : dp[b][a] = b_enc[a] + sum_d dec[b][d]*W_dec[d][a]
// blocks 64..127 : Wt[a][e] = bf16(W_enc[e][a])   (transposed, B-frag friendly)
__global__ __launch_bounds__(256) void prep_kernel(
    const float* __restrict__ dec, const float* __restrict__ W_enc,
    const float* __restrict__ b_enc, const float* __restrict__ W_dec,
    float* __restrict__ dp, unsigned short* __restrict__ Wt)
{
    const int bid = blockIdx.x, tid = threadIdx.x;
    if (bid < B_SZ) {
        float s = b_enc[tid];
        const float* dr = dec + bid * D_DIM;
        #pragma unroll 8
        for (int d = 0; d < D_DIM; ++d)
            s = fmaf(dr[d], W_dec[d * A_DIM + tid], s);
        dp[bid * A_DIM + tid] = s;
    } else {
        int base = (bid - B_SZ) * 2048;
        #pragma unroll
        for (int i = 0; i < 8; ++i) {
            int idx = base + tid + i * 256;       // idx = a*512 + e
            int a = idx >> 9, e = idx & 511;
            Wt[idx] = f2bf(W_enc[e * A_DIM + a]);
        }
    }
}

// ---------------- Kernel 2: main (GEMM + tanh·v + exp + partial context) -----
// 512 threads (8 waves), 2 blocks/CU (LDS ~75 KB) -> 16 waves/CU.
// Wave w owns N-cols [w*32, w*32+32); all waves share the staged A tile.
__global__ __launch_bounds__(512, 4) void attn_main(
    const float* __restrict__ enc, const unsigned short* __restrict__ Wt,
    const float* __restrict__ dpg, const float* __restrict__ vatt,
    float* __restrict__ u_out, float* __restrict__ ctx_part)
{
    const int tb = blockIdx.x, b = blockIdx.y;
    const int tid = threadIdx.x;
    __shared__ unsigned short tile[TT * LDT];     // 66,560 B
    __shared__ float spart[8][TT];                // 2 KB
    __shared__ float uu[TT];
    __shared__ float dp_s[A_DIM];
    __shared__ float vv[A_DIM];
    __shared__ float ctx_red[E_DIM];              // 2 KB (t-half-1 partials)

    if (tid < A_DIM) {
        dp_s[tid] = dpg[b * A_DIM + tid];
        vv[tid]   = vatt[tid];
    }

    // stage enc tile: 64 rows x 512 f32 -> bf16 LDS (8192 float4, 16/thread)
    const float4* src = (const float4*)(enc + ((size_t)b * T_SZ + (size_t)tb * TT) * E_DIM);
    #pragma unroll 4
    for (int it = 0; it < 16; ++it) {
        int idx = tid + it * 512;                 // float4 index over 64*128
        int r = idx >> 7, c = idx & 127;
        float4 v4 = src[idx];
        ushort4 h;
        h.x = f2bf(v4.x); h.y = f2bf(v4.y); h.z = f2bf(v4.z); h.w = f2bf(v4.w);
        *(ushort4*)&tile[r * LDT + c * 4] = h;
    }
    __syncthreads();

    // GEMM: M=64(t) x N=256(a) x K=512(e); wave w -> cols [w*32, w*32+32)
    const int w = tid >> 6, lane = tid & 63;
    const int m16 = lane & 15, q = lane >> 4;
    f32x4 acc[4][2];
    #pragma unroll
    for (int mi = 0; mi < 4; ++mi)
        #pragma unroll
        for (int ni = 0; ni < 2; ++ni)
            acc[mi][ni] = (f32x4){0.f, 0.f, 0.f, 0.f};

    const unsigned short* WtW = Wt + (size_t)(w * 32) * E_DIM;
    #pragma unroll 2
    for (int k0 = 0; k0 < E_DIM; k0 += 32) {
        const int ka = k0 + q * 8;
        bf16x8 afr[4], bfr[2];
        #pragma unroll
        for (int ni = 0; ni < 2; ++ni)
            bfr[ni] = *(const bf16x8*)&WtW[(ni * 16 + m16) * E_DIM + ka];
        #pragma unroll
        for (int mi = 0; mi < 4; ++mi)
            afr[mi] = *(const bf16x8*)&tile[(mi * 16 + m16) * LDT + ka];
        #pragma unroll
        for (int mi = 0; mi < 4; ++mi)
            #pragma unroll
            for (int ni = 0; ni < 2; ++ni)
                acc[mi][ni] = __builtin_amdgcn_mfma_f32_16x16x32_bf16(
                    afr[mi], bfr[ni], acc[mi][ni], 0, 0, 0);
    }

    // epilogue: score_t = sum_a v[a]*tanh(proj + dp[a])   (b_att cancels in softmax)
    float va[2], dpv[2];
    #pragma unroll
    for (int ni = 0; ni < 2; ++ni) {
        int a = w * 32 + ni * 16 + m16;
        va[ni] = vv[a]; dpv[ni] = dp_s[a];
    }
    #pragma unroll
    for (int mi = 0; mi < 4; ++mi) {
        #pragma unroll
        for (int r = 0; r < 4; ++r) {
            float p = va[0] * tanh_fast(acc[mi][0][r] + dpv[0])
                    + va[1] * tanh_fast(acc[mi][1][r] + dpv[1]);
            p += __shfl_xor(p, 1); p += __shfl_xor(p, 2);
            p += __shfl_xor(p, 4); p += __shfl_xor(p, 8);
            if (m16 == 0) spart[w][mi * 16 + q * 4 + r] = p;
        }
    }
    __syncthreads();

    if (tid < TT) {
        float s = 0.f;
        #pragma unroll
        for (int w8 = 0; w8 < 8; ++w8) s += spart[w8][tid];
        float e = __expf(s);                      // |s| <= 16.06 -> safe
        uu[tid] = e;
        u_out[(size_t)b * T_SZ + (size_t)tb * TT + tid] = e;
    }
    __syncthreads();

    // partial context from resident LDS tile:
    // thread owns col pair (2*c2, 2*c2+1), t-half h: t in [h*32, h*32+32)
    {
        const int c2 = tid & 255, h = tid >> 8;
        float c0 = 0.f, c1 = 0.f;
        #pragma unroll 8
        for (int i = 0; i < 32; ++i) {
            int t = h * 32 + i;
            float ut = uu[t];
            unsigned int pk = *(const unsigned int*)&tile[t * LDT + 2 * c2];
            c0 = fmaf(ut, bf_lo(pk), c0);
            c1 = fmaf(ut, bf_hi(pk), c1);
        }
        if (h == 1) { ctx_red[2 * c2] = c0; ctx_red[2 * c2 + 1] = c1; }
        __syncthreads();
        if (h == 0) {
            c0 += ctx_red[2 * c2];
            c1 += ctx_red[2 * c2 + 1];
            float2 st; st.x = c0; st.y = c1;
            ((float2*)(ctx_part + ((size_t)tb * B_SZ + b) * E_DIM))[c2] = st;
        }
    }
}

// ---------------- Kernel 3: finalize (softmax denom, weights, context) -------
__global__ __launch_bounds__(256) void finalize_kernel(
    const float* __restrict__ u, const float* __restrict__ ctx_part,
    float* __restrict__ out)
{
    const int b = blockIdx.x, tid = threadIdx.x;
    __shared__ float red[256];
    const float* ub = u + (size_t)b * T_SZ;
    float s = 0.f;
    for (int i = tid; i < T_SZ; i += 256) s += ub[i];
    red[tid] = s; __syncthreads();
    for (int st = 128; st > 0; st >>= 1) {
        if (tid < st) red[tid] += red[tid + st];
        __syncthreads();
    }
    const float invS = 1.0f / red[0];
    // attention weights -> out[32768 ..)
    float* wout = out + B_SZ * E_DIM + (size_t)b * T_SZ;
    for (int i = tid; i < T_SZ; i += 256) wout[i] = ub[i] * invS;
    // context -> out[0 .. 32768)
    for (int e = tid; e < E_DIM; e += 256) {
        float c = 0.f;
        #pragma unroll 8
        for (int t = 0; t < NTB; ++t)
            c += ctx_part[((size_t)t * B_SZ + b) * E_DIM + e];
        out[(size_t)b * E_DIM + e] = c * invS;
    }
}

extern "C" void kernel_launch(void* const* d_in, const int* in_sizes, int n_in,
                              void* d_out, int out_size, void* d_ws, size_t ws_size,
                              hipStream_t stream) {
    const float* enc   = (const float*)d_in[0];   // (64,4096,512)
    const float* dec   = (const float*)d_in[1];   // (64,512)
    const float* W_enc = (const float*)d_in[2];   // (512,256)
    const float* b_enc = (const float*)d_in[3];   // (256,)
    const float* W_dec = (const float*)d_in[4];   // (512,256)
    const float* v_att = (const float*)d_in[5];   // (256,)
    // d_in[6] = b_att: constant shift of all scores -> cancels in softmax.
    float* out = (float*)d_out;                   // [context 64*512 | weights 64*4096]

    // ws layout (bytes): Wt bf16 [0,262144) | dp [262144,327680)
    //                    | u [327680,1376256) | ctx_part [1376256, +8MiB)
    char* ws = (char*)d_ws;
    unsigned short* Wt = (unsigned short*)(ws);
    float* dp          = (float*)(ws + 262144);
    float* u           = (float*)(ws + 327680);
    float* ctx_part    = (float*)(ws + 1376256);

    prep_kernel<<<128, 256, 0, stream>>>(dec, W_enc, b_enc, W_dec, dp, Wt);
    attn_main<<<dim3(NTB, B_SZ), 512, 0, stream>>>(enc, Wt, dp, v_att, u, ctx_part);
    finalize_kernel<<<B_SZ, 256, 0, stream>>>(u, ctx_part, out);
}